// Round 8
// baseline (339.668 us; speedup 1.0000x reference)
//
#include <hip/hip_runtime.h>
#include <hip/hip_cooperative_groups.h>
#include <math.h>

namespace cg = cooperative_groups;

#define N_NODES 50000
#define DEG 16
#define IN_F 256
#define NH 4
#define OUT_F 64
#define HF 256          // NH * OUT_F
#define NEG_SLOPE 0.2f
#define N_TILES ((N_NODES + 63) / 64)     // 782 gemm M-tiles
#define N_AGGB  (N_NODES / 4)             // 12500 agg virtual blocks

typedef float  floatx4 __attribute__((ext_vector_type(4)));
typedef short  short8  __attribute__((ext_vector_type(8)));

__device__ __forceinline__ ushort f2bf(float x) {   // RNE fp32->bf16
    unsigned u = __float_as_uint(x);
    u = (u + 0x7FFFu + ((u >> 16) & 1u)) >> 16;
    return (ushort)u;
}
__device__ __forceinline__ float bf2f(ushort b) {
    return __uint_as_float(((unsigned)b) << 16);
}
__device__ __forceinline__ void gld16(const void* g, void* l) {
    __builtin_amdgcn_global_load_lds((const __attribute__((address_space(1))) void*)g,
                                     (__attribute__((address_space(3))) void*)l, 16, 0, 0);
}

#define STAGE_A8(dst, v0, v1) do { short8 a8_;                        \
    a8_[0] = (short)f2bf((v0).x); a8_[1] = (short)f2bf((v0).y);       \
    a8_[2] = (short)f2bf((v0).z); a8_[3] = (short)f2bf((v0).w);       \
    a8_[4] = (short)f2bf((v1).x); a8_[5] = (short)f2bf((v1).y);       \
    a8_[6] = (short)f2bf((v1).z); a8_[7] = (short)f2bf((v1).w);       \
    *(short8*)(dst) = a8_; } while (0)

// ================= device bodies (shared by fused + standalone) =============

// ---- W[256,256] fp32 -> Wt[n][k] bf16 (transposed); bid in [0,16) ----
__device__ __forceinline__ void cast_body(const float* __restrict__ W,
                                          ushort* __restrict__ Wt,
                                          int bid, ushort* smem_u) {
    float (*tile)[65] = reinterpret_cast<float(*)[65]>(smem_u);
    const int bx = bid & 3;    // n tile
    const int by = bid >> 2;   // k tile
#pragma unroll
    for (int i = 0; i < 16; ++i) {
        int idx = threadIdx.x + 256 * i;
        int r = idx >> 6, c = idx & 63;
        tile[r][c] = W[(by * 64 + r) * 256 + bx * 64 + c];
    }
    __syncthreads();
#pragma unroll
    for (int i = 0; i < 16; ++i) {
        int idx = threadIdx.x + 256 * i;
        int n = idx >> 6, k = idx & 63;
        Wt[(size_t)(bx * 64 + n) * 256 + by * 64 + k] = f2bf(tile[k][n]);
    }
}

// ---- MFMA GEMM tile body (R3 version).  64x256 block tile, 4 waves 2x2,
// acc 2x8 frags 16x16x32, double-buffered LDS, one barrier per K-step. ----
__device__ __forceinline__ void gemm_body(const float* __restrict__ A,
                                          const ushort* __restrict__ Bt,
                                          const float* __restrict__ attn_l,
                                          const float* __restrict__ attn_r,
                                          ushort* __restrict__ H,
                                          float* __restrict__ arow_g,
                                          float* __restrict__ acol_g,
                                          int M, int bx, ushort* smem) {
    __syncthreads();            // prev phase's LDS reads done before we write
    ushort* Ab[2] = { smem,         smem + 10240 };
    ushort* Bb[2] = { smem + 2048,  smem + 12288 };

    const int tid  = threadIdx.x;
    const int w    = tid >> 6;
    const int lane = tid & 63;
    const int wm   = w >> 1, wn = w & 1;
    const int g    = lane >> 4;
    const int r    = lane & 15;

    const int m0 = bx * 64;

    const int srow = tid >> 2;
    const int kc8  = (tid & 3) * 8;
    const int gmA  = min(m0 + srow, M - 1);
    const float*  Aptr = A  + (size_t)gmA  * 256 + kc8;
    const ushort* Bptr = Bt + (size_t)srow * 256 + kc8;

    floatx4 acc[2][8];
#pragma unroll
    for (int i = 0; i < 2; ++i)
#pragma unroll
        for (int j = 0; j < 8; ++j) acc[i][j] = (floatx4)(0.f);

    {
        float4 t0 = *(const float4*)(Aptr);
        float4 t1 = *(const float4*)(Aptr + 4);
        STAGE_A8(Ab[0] + tid * 8, t0, t1);
        gld16(Bptr,             Bb[0] +        tid * 8);
        gld16(Bptr +  64 * 256, Bb[0] + 2048 + tid * 8);
        gld16(Bptr + 128 * 256, Bb[0] + 4096 + tid * 8);
        gld16(Bptr + 192 * 256, Bb[0] + 6144 + tid * 8);
    }
    float4 qx[2], qy[2];
    qx[1] = *(const float4*)(Aptr + 32);  qy[1] = *(const float4*)(Aptr + 36);
    qx[0] = *(const float4*)(Aptr + 64);  qy[0] = *(const float4*)(Aptr + 68);
    __syncthreads();

#pragma unroll
    for (int kk = 0; kk < 8; ++kk) {
        ushort* Ac = Ab[kk & 1];
        ushort* Bc = Bb[kk & 1];
        if (kk < 7) {
            const int nb = (kk + 1) & 1;
            STAGE_A8(Ab[nb] + tid * 8, qx[nb], qy[nb]);
            const ushort* bsrc = Bptr + (kk + 1) * 32;
            gld16(bsrc,             Bb[nb] +        tid * 8);
            gld16(bsrc +  64 * 256, Bb[nb] + 2048 + tid * 8);
            gld16(bsrc + 128 * 256, Bb[nb] + 4096 + tid * 8);
            gld16(bsrc + 192 * 256, Bb[nb] + 6144 + tid * 8);
        }
        if (kk < 5) {
            const int lb = (kk + 3) & 1;
            qx[lb] = *(const float4*)(Aptr + (kk + 3) * 32);
            qy[lb] = *(const float4*)(Aptr + (kk + 3) * 32 + 4);
        }

        short8 af[2], bfr[8];
#pragma unroll
        for (int i = 0; i < 2; ++i)
            af[i] = *(const short8*)&Ac[(size_t)(wm * 32 + i * 16 + r) * 32 + g * 8];
#pragma unroll
        for (int j = 0; j < 8; ++j)
            bfr[j] = *(const short8*)&Bc[(size_t)(wn * 128 + j * 16 + r) * 32 + g * 8];
#pragma unroll
        for (int i = 0; i < 2; ++i)
#pragma unroll
            for (int j = 0; j < 8; ++j)
                acc[i][j] = __builtin_amdgcn_mfma_f32_16x16x32_bf16(af[i], bfr[j], acc[i][j], 0, 0, 0);

        __syncthreads();
    }

    // ---- epilogue: per-wave LDS transpose; C/D layout col=r, row=g*4+reg ----
    float* wreg = (float*)smem + w * 1024;
    const int rr = lane >> 2;
    const int cb = (lane & 3) * 16;

#pragma unroll
    for (int h = 0; h < 2; ++h) {
        const int head = wn * 2 + h;
        float al[16], ar[16];
#pragma unroll
        for (int q = 0; q < 4; ++q) {
            *(float4*)&al[q * 4] = *(const float4*)(attn_l + head * 64 + cb + q * 4);
            *(float4*)&ar[q * 4] = *(const float4*)(attn_r + head * 64 + cb + q * 4);
        }
#pragma unroll
        for (int i = 0; i < 2; ++i) {
#pragma unroll
            for (int j = 0; j < 4; ++j)
#pragma unroll
                for (int reg = 0; reg < 4; ++reg)
                    wreg[(g * 4 + reg) * 64 + j * 16 + r] = acc[i][h * 4 + j][reg];

            float v[16];
#pragma unroll
            for (int q = 0; q < 4; ++q)
                *(float4*)&v[q * 4] = *(const float4*)&wreg[rr * 64 + cb + q * 4];

            float pl = 0.f, pr = 0.f;
#pragma unroll
            for (int k = 0; k < 16; ++k) { pl += v[k] * al[k]; pr += v[k] * ar[k]; }
            pl += __shfl_xor(pl, 1); pl += __shfl_xor(pl, 2);
            pr += __shfl_xor(pr, 1); pr += __shfl_xor(pr, 2);

            const int gm = m0 + wm * 32 + i * 16 + rr;
            if (gm < M) {
                short8 h0, h1;
#pragma unroll
                for (int k = 0; k < 8; ++k) { h0[k] = (short)f2bf(v[k]); h1[k] = (short)f2bf(v[8 + k]); }
                ushort* dst = H + (size_t)gm * 256 + wn * 128 + h * 64 + cb;
                *(short8*)dst       = h0;
                *(short8*)(dst + 8) = h1;
                if ((lane & 3) == 0) {
                    arow_g[gm * NH + head] = pl;
                    acol_g[gm * NH + head] = pr;
                }
            }
        }
    }
}

// ---- fused softmax+aggregate body (R3 best: 1 dst/wave, 8-slot LDS) ----
// smem: needs 16384 ushorts (wave-private 8KB regions).  No __syncthreads.
__device__ __forceinline__ void agg_body(const int* __restrict__ col_ind,
                                         const ushort* __restrict__ H,
                                         const float* __restrict__ arow_g,
                                         const float* __restrict__ acol_g,
                                         float* __restrict__ out,
                                         int vb, ushort* smem) {
    const int wave = threadIdx.x >> 6, lane = threadIdx.x & 63;
    const int d0   = vb * 4 + wave;
    const int hidx = lane >> 4, e_s = lane & 15;

    int src0 = col_ind[d0 * DEG + e_s];
    src0 = src0 < 0 ? 0 : (src0 >= N_NODES ? N_NODES - 1 : src0);

    // score loads first (older in vm FIFO than all gathers)
    const float sc_r0 = arow_g[d0 * NH + hidx];
    const float sc_c0 = acol_g[src0 * NH + hidx];
    __builtin_amdgcn_sched_barrier(0);

    const int fb     = (lane & 31) * 8;
    const int head_a = (lane & 31) >> 3;
    const int half   = lane >> 5;

    ushort* lbase = smem + wave * 4096;
#pragma unroll
    for (int t = 0; t < 8; ++t) {
        const int e  = 2 * t + half;
        const int r0 = __shfl(src0, e);
        gld16(H + (size_t)r0 * 256 + fb, lbase + t * 512 + lane * 8);
    }
    __builtin_amdgcn_sched_barrier(0);

    // softmax under the in-flight gathers
    float s0 = sc_r0 + sc_c0;
    s0 = (s0 >= 0.f) ? s0 : NEG_SLOPE * s0;
    float m0 = s0;
#pragma unroll
    for (int off = 1; off < 16; off <<= 1)
        m0 = fmaxf(m0, __shfl_xor(m0, off));
    float ex0 = expf(s0 - m0);
    float su0 = ex0;
#pragma unroll
    for (int off = 1; off < 16; off <<= 1)
        su0 += __shfl_xor(su0, off);
    const float alpha0 = ex0 / su0;

    float a0[8];
#pragma unroll
    for (int t = 0; t < 8; ++t)
        a0[t] = __shfl(alpha0, head_a * 16 + 2 * t + half);

    asm volatile("s_waitcnt vmcnt(0)" ::: "memory");
    __builtin_amdgcn_sched_barrier(0);

    float acc0[8];
#pragma unroll
    for (int k = 0; k < 8; ++k) acc0[k] = 0.f;
#pragma unroll
    for (int t = 0; t < 8; ++t) {
        short8 hv = *(const short8*)(lbase + t * 512 + lane * 8);
#pragma unroll
        for (int k = 0; k < 8; ++k)
            acc0[k] += a0[t] * bf2f((ushort)hv[k]);
    }
#pragma unroll
    for (int k = 0; k < 8; ++k)
        acc0[k] += __shfl_xor(acc0[k], 32);

    const int qb = half * 4;
    *(float4*)(out + (size_t)d0 * 256 + fb + qb) =
        make_float4(acc0[qb], acc0[qb + 1], acc0[qb + 2], acc0[qb + 3]);
}

// ================= fused cooperative kernel =================================
// One launch: cast (blocks 0-15) -> grid.sync -> gemm (grid-stride over 782
// tiles) -> grid.sync -> agg (grid-stride over 12500 virtual blocks).
// 512 blocks x 256 thr: guaranteed co-resident (40KB LDS -> 4 blk/CU by LDS;
// __launch_bounds__(256,2) caps VGPR at 2 blk/CU minimum -> 512 fits).
__global__ __launch_bounds__(256, 2) void fused_kernel(const int* __restrict__ col_ind,
                                                       const float* __restrict__ feat,
                                                       const float* __restrict__ W,
                                                       const float* __restrict__ attn_l,
                                                       const float* __restrict__ attn_r,
                                                       ushort* __restrict__ Wt,
                                                       ushort* __restrict__ H,
                                                       float* __restrict__ arow,
                                                       float* __restrict__ acol,
                                                       float* __restrict__ out) {
    __shared__ __align__(16) ushort smem[20480];   // 40 KB
    cg::grid_group grid = cg::this_grid();

    if (blockIdx.x < 16)
        cast_body(W, Wt, blockIdx.x, smem);
    grid.sync();

    for (int bx = blockIdx.x; bx < N_TILES; bx += gridDim.x)
        gemm_body(feat, Wt, attn_l, attn_r, H, arow, acol, N_NODES, bx, smem);
    grid.sync();

    for (int vb = blockIdx.x; vb < N_AGGB; vb += gridDim.x)
        agg_body(col_ind, H, arow, acol, out, vb, smem);
}

// ================= standalone fallback kernels ==============================
__global__ __launch_bounds__(256) void cast_wt_kernel(const float* __restrict__ W,
                                                      ushort* __restrict__ Wt) {
    __shared__ __align__(16) ushort smem[8320];
    cast_body(W, Wt, blockIdx.x, smem);
}

__global__ __launch_bounds__(256) void mfma_gemm_kernel(const float* __restrict__ A,
                                                        const ushort* __restrict__ Bt,
                                                        const float* __restrict__ attn_l,
                                                        const float* __restrict__ attn_r,
                                                        ushort* __restrict__ H,
                                                        float* __restrict__ arow_g,
                                                        float* __restrict__ acol_g,
                                                        int M) {
    __shared__ __align__(16) ushort smem[20480];
    gemm_body(A, Bt, attn_l, attn_r, H, arow_g, acol_g, M, blockIdx.x, smem);
}

__global__ __launch_bounds__(256) void agg_kernel(const int* __restrict__ col_ind,
                                                  const ushort* __restrict__ H,
                                                  const float* __restrict__ arow_g,
                                                  const float* __restrict__ acol_g,
                                                  float* __restrict__ out) {
    __shared__ __align__(16) ushort smem[16384];
    agg_body(col_ind, H, arow_g, acol_g, out, blockIdx.x, smem);
}

extern "C" void kernel_launch(void* const* d_in, const int* in_sizes, int n_in,
                              void* d_out, int out_size, void* d_ws, size_t ws_size,
                              hipStream_t stream) {
    const int*   col_ind = (const int*)d_in[1];
    const float* feat    = (const float*)d_in[4];
    const float* W       = (const float*)d_in[5];
    const float* attn_l  = (const float*)d_in[6];
    const float* attn_r  = (const float*)d_in[7];
    float* out = (float*)d_out;

    // ws: Wt 128KB | h_bf 25.6MB | arow 0.8MB | acol 0.8MB
    ushort* Wt   = (ushort*)d_ws;
    ushort* h_bf = Wt + 256 * 256;
    float*  arow = (float*)(h_bf + (size_t)N_NODES * HF);
    float*  acol = arow + (size_t)N_NODES * NH;

    const size_t need = (256 * 256 + (size_t)N_NODES * HF) * 2
                      + (size_t)N_NODES * NH * 4 * 2;
    if (ws_size < need) return;

    void* args[] = { (void*)&col_ind, (void*)&feat, (void*)&W,
                     (void*)&attn_l, (void*)&attn_r,
                     (void*)&Wt, (void*)&h_bf, (void*)&arow, (void*)&acol,
                     (void*)&out };
    hipError_t err = hipLaunchCooperativeKernel((const void*)fused_kernel,
                                                dim3(512), dim3(256),
                                                args, 0, stream);
    if (err != hipSuccess) {
        (void)hipGetLastError();   // clear sticky error; fall back to 3 launches
        cast_wt_kernel<<<16, 256, 0, stream>>>(W, Wt);
        mfma_gemm_kernel<<<N_TILES, 256, 0, stream>>>(feat, Wt, attn_l, attn_r,
                                                      h_bf, arow, acol, N_NODES);
        agg_kernel<<<N_AGGB, 256, 0, stream>>>(col_ind, h_bf, arow, acol, out);
    }
}

// Round 9
// 186.840 us; speedup vs baseline: 1.8180x; 1.8180x over previous
//
#include <hip/hip_runtime.h>
#include <math.h>

#define N_NODES 50000
#define DEG 16
#define IN_F 256
#define NH 4
#define OUT_F 64
#define HF 256          // NH * OUT_F
#define NEG_SLOPE 0.2f

typedef float  floatx4 __attribute__((ext_vector_type(4)));
typedef short  short8  __attribute__((ext_vector_type(8)));

__device__ __forceinline__ ushort f2bf(float x) {   // RNE fp32->bf16
    unsigned u = __float_as_uint(x);
    u = (u + 0x7FFFu + ((u >> 16) & 1u)) >> 16;
    return (ushort)u;
}
__device__ __forceinline__ float bf2f(ushort b) {
    return __uint_as_float(((unsigned)b) << 16);
}
__device__ __forceinline__ void gld16(const void* g, void* l) {
    __builtin_amdgcn_global_load_lds((const __attribute__((address_space(1))) void*)g,
                                     (__attribute__((address_space(3))) void*)l, 16, 0, 0);
}

// ---- W[256,256] fp32 -> Wt[n][k] bf16 (transposed) ----
__global__ __launch_bounds__(256) void cast_wt_kernel(const float* __restrict__ W,
                                                      ushort* __restrict__ Wt) {
    __shared__ float tile[64][65];
    const int bx = blockIdx.x & 3;    // n tile
    const int by = blockIdx.x >> 2;   // k tile
#pragma unroll
    for (int i = 0; i < 16; ++i) {
        int idx = threadIdx.x + 256 * i;
        int r = idx >> 6, c = idx & 63;
        tile[r][c] = W[(by * 64 + r) * 256 + bx * 64 + c];
    }
    __syncthreads();
#pragma unroll
    for (int i = 0; i < 16; ++i) {
        int idx = threadIdx.x + 256 * i;
        int n = idx >> 6, k = idx & 63;
        Wt[(size_t)(bx * 64 + n) * 256 + by * 64 + k] = f2bf(tile[k][n]);
    }
}

// ---- MFMA GEMM, full-N single pass, double-buffered LDS ----
// H[M,256] = bf16(A_f32) @ W   (B given as Wt[n][k] bf16)
// 64x256 block tile, 4 waves 2x2 (wave tile 32x128), acc 2x8 frags of 16x16x32.
__global__ __launch_bounds__(256) void mfma_gemm_kernel(const float* __restrict__ A,
                                                        const ushort* __restrict__ Bt,
                                                        const float* __restrict__ attn_l,
                                                        const float* __restrict__ attn_r,
                                                        ushort* __restrict__ H,
                                                        float* __restrict__ arow_g,
                                                        float* __restrict__ acol_g,
                                                        int M) {
    __shared__ __align__(16) ushort smem[20480];
    ushort* Ab[2] = { smem,         smem + 10240 };
    ushort* Bb[2] = { smem + 2048,  smem + 12288 };

    const int tid  = threadIdx.x;
    const int w    = tid >> 6;
    const int lane = tid & 63;
    const int wm   = w >> 1, wn = w & 1;
    const int g    = lane >> 4;     // k-chunk group (8 bf16 each)
    const int r    = lane & 15;

    const int m0 = blockIdx.x * 64;

    const int srow = tid >> 2;
    const int kc8  = (tid & 3) * 8;
    const int gmA  = min(m0 + srow, M - 1);
    const float*  Aptr = A  + (size_t)gmA  * 256 + kc8;
    const ushort* Bptr = Bt + (size_t)srow * 256 + kc8;

    floatx4 acc[2][8];
#pragma unroll
    for (int i = 0; i < 2; ++i)
#pragma unroll
        for (int j = 0; j < 8; ++j) acc[i][j] = (floatx4)(0.f);

    float4 p0 = *(const float4*)(Aptr);
    float4 p1 = *(const float4*)(Aptr + 4);

    {
        short8 a8;
        a8[0] = (short)f2bf(p0.x); a8[1] = (short)f2bf(p0.y);
        a8[2] = (short)f2bf(p0.z); a8[3] = (short)f2bf(p0.w);
        a8[4] = (short)f2bf(p1.x); a8[5] = (short)f2bf(p1.y);
        a8[6] = (short)f2bf(p1.z); a8[7] = (short)f2bf(p1.w);
        *(short8*)(Ab[0] + tid * 8) = a8;
        gld16(Bptr,             Bb[0] +        tid * 8);
        gld16(Bptr +  64 * 256, Bb[0] + 2048 + tid * 8);
        gld16(Bptr + 128 * 256, Bb[0] + 4096 + tid * 8);
        gld16(Bptr + 192 * 256, Bb[0] + 6144 + tid * 8);
    }
    p0 = *(const float4*)(Aptr + 32);
    p1 = *(const float4*)(Aptr + 36);
    __syncthreads();

#pragma unroll
    for (int kk = 0; kk < 8; ++kk) {
        ushort* Ac = Ab[kk & 1];
        ushort* Bc = Bb[kk & 1];
        if (kk < 7) {
            ushort* An = Ab[(kk + 1) & 1];
            ushort* Bn = Bb[(kk + 1) & 1];
            short8 a8;
            a8[0] = (short)f2bf(p0.x); a8[1] = (short)f2bf(p0.y);
            a8[2] = (short)f2bf(p0.z); a8[3] = (short)f2bf(p0.w);
            a8[4] = (short)f2bf(p1.x); a8[5] = (short)f2bf(p1.y);
            a8[6] = (short)f2bf(p1.z); a8[7] = (short)f2bf(p1.w);
            *(short8*)(An + tid * 8) = a8;
            const ushort* bsrc = Bptr + (kk + 1) * 32;
            gld16(bsrc,             Bn +        tid * 8);
            gld16(bsrc +  64 * 256, Bn + 2048 + tid * 8);
            gld16(bsrc + 128 * 256, Bn + 4096 + tid * 8);
            gld16(bsrc + 192 * 256, Bn + 6144 + tid * 8);
        }
        if (kk < 6) {
            p0 = *(const float4*)(Aptr + (kk + 2) * 32);
            p1 = *(const float4*)(Aptr + (kk + 2) * 32 + 4);
        }

        short8 af[2], bfr[8];
#pragma unroll
        for (int i = 0; i < 2; ++i)
            af[i] = *(const short8*)&Ac[(size_t)(wm * 32 + i * 16 + r) * 32 + g * 8];
#pragma unroll
        for (int j = 0; j < 8; ++j)
            bfr[j] = *(const short8*)&Bc[(size_t)(wn * 128 + j * 16 + r) * 32 + g * 8];
#pragma unroll
        for (int i = 0; i < 2; ++i)
#pragma unroll
            for (int j = 0; j < 8; ++j)
                acc[i][j] = __builtin_amdgcn_mfma_f32_16x16x32_bf16(af[i], bfr[j], acc[i][j], 0, 0, 0);

        __syncthreads();
    }

    // ---- epilogue: per-wave LDS transpose; C/D layout col=r, row=g*4+reg ----
    float* wreg = (float*)smem + w * 1024;
    const int rr = lane >> 2;
    const int cb = (lane & 3) * 16;

#pragma unroll
    for (int h = 0; h < 2; ++h) {
        const int head = wn * 2 + h;
        float al[16], ar[16];
#pragma unroll
        for (int q = 0; q < 4; ++q) {
            *(float4*)&al[q * 4] = *(const float4*)(attn_l + head * 64 + cb + q * 4);
            *(float4*)&ar[q * 4] = *(const float4*)(attn_r + head * 64 + cb + q * 4);
        }
#pragma unroll
        for (int i = 0; i < 2; ++i) {
#pragma unroll
            for (int j = 0; j < 4; ++j)
#pragma unroll
                for (int reg = 0; reg < 4; ++reg)
                    wreg[(g * 4 + reg) * 64 + j * 16 + r] = acc[i][h * 4 + j][reg];

            float v[16];
#pragma unroll
            for (int q = 0; q < 4; ++q)
                *(float4*)&v[q * 4] = *(const float4*)&wreg[rr * 64 + cb + q * 4];

            float pl = 0.f, pr = 0.f;
#pragma unroll
            for (int k = 0; k < 16; ++k) { pl += v[k] * al[k]; pr += v[k] * ar[k]; }
            pl += __shfl_xor(pl, 1); pl += __shfl_xor(pl, 2);
            pr += __shfl_xor(pr, 1); pr += __shfl_xor(pr, 2);

            const int gm = m0 + wm * 32 + i * 16 + rr;
            if (gm < M) {
                short8 h0, h1;
#pragma unroll
                for (int k = 0; k < 8; ++k) { h0[k] = (short)f2bf(v[k]); h1[k] = (short)f2bf(v[8 + k]); }
                ushort* dst = H + (size_t)gm * 256 + wn * 128 + h * 64 + cb;
                *(short8*)dst       = h0;
                *(short8*)(dst + 8) = h1;
                if ((lane & 3) == 0) {
                    arow_g[gm * NH + head] = pl;
                    acol_g[gm * NH + head] = pr;
                }
            }
        }
    }
}

// ---- fused softmax+aggregate: 2 dsts per wave (R1 best: 64.6/63.3 µs band) ----
__global__ __launch_bounds__(256) void agg_kernel(const int* __restrict__ col_ind,
                                                  const ushort* __restrict__ H,
                                                  const float* __restrict__ arow_g,
                                                  const float* __restrict__ acol_g,
                                                  float* __restrict__ out) {
    const int wave = threadIdx.x >> 6, lane = threadIdx.x & 63;
    const int d0   = blockIdx.x * 8 + wave * 2;
    const int d1   = d0 + 1;
    const int hidx = lane >> 4, e_s = lane & 15;

    int src0 = col_ind[d0 * DEG + e_s];
    int src1 = col_ind[d1 * DEG + e_s];
    src0 = src0 < 0 ? 0 : (src0 >= N_NODES ? N_NODES - 1 : src0);
    src1 = src1 < 0 ? 0 : (src1 >= N_NODES ? N_NODES - 1 : src1);

    float s0 = arow_g[d0 * NH + hidx] + acol_g[src0 * NH + hidx];
    float s1 = arow_g[d1 * NH + hidx] + acol_g[src1 * NH + hidx];
    s0 = (s0 >= 0.f) ? s0 : NEG_SLOPE * s0;
    s1 = (s1 >= 0.f) ? s1 : NEG_SLOPE * s1;
    float m0 = s0, m1 = s1;
#pragma unroll
    for (int off = 1; off < 16; off <<= 1) {
        m0 = fmaxf(m0, __shfl_xor(m0, off));
        m1 = fmaxf(m1, __shfl_xor(m1, off));
    }
    float ex0 = expf(s0 - m0), ex1 = expf(s1 - m1);
    float su0 = ex0, su1 = ex1;
#pragma unroll
    for (int off = 1; off < 16; off <<= 1) {
        su0 += __shfl_xor(su0, off);
        su1 += __shfl_xor(su1, off);
    }
    const float alpha0 = ex0 / su0, alpha1 = ex1 / su1;

    const int fb     = (lane & 31) * 8;
    const int head_a = fb >> 6;
    const int half   = lane >> 5;

    short8 hv0[8], hv1[8];
#pragma unroll
    for (int t = 0; t < DEG / 2; ++t) {
        const int e  = 2 * t + half;
        const int r0 = __shfl(src0, e);
        const int r1 = __shfl(src1, e);
        hv0[t] = *(const short8*)(H + (size_t)r0 * 256 + fb);
        hv1[t] = *(const short8*)(H + (size_t)r1 * 256 + fb);
    }
    float a0[8], a1[8];
#pragma unroll
    for (int t = 0; t < DEG / 2; ++t) {
        const int e = 2 * t + half;
        a0[t] = __shfl(alpha0, head_a * 16 + e);
        a1[t] = __shfl(alpha1, head_a * 16 + e);
    }
    float acc0[8], acc1[8];
#pragma unroll
    for (int k = 0; k < 8; ++k) { acc0[k] = 0.f; acc1[k] = 0.f; }
#pragma unroll
    for (int t = 0; t < DEG / 2; ++t) {
#pragma unroll
        for (int k = 0; k < 8; ++k) {
            acc0[k] += a0[t] * bf2f((ushort)hv0[t][k]);
            acc1[k] += a1[t] * bf2f((ushort)hv1[t][k]);
        }
    }
#pragma unroll
    for (int k = 0; k < 8; ++k) {
        acc0[k] += __shfl_xor(acc0[k], 32);
        acc1[k] += __shfl_xor(acc1[k], 32);
    }

    const int qb = half * 4;
    *(float4*)(out + (size_t)d0 * 256 + fb + qb) =
        make_float4(acc0[qb], acc0[qb + 1], acc0[qb + 2], acc0[qb + 3]);
    *(float4*)(out + (size_t)d1 * 256 + fb + qb) =
        make_float4(acc1[qb], acc1[qb + 1], acc1[qb + 2], acc1[qb + 3]);
}

extern "C" void kernel_launch(void* const* d_in, const int* in_sizes, int n_in,
                              void* d_out, int out_size, void* d_ws, size_t ws_size,
                              hipStream_t stream) {
    const int*   col_ind = (const int*)d_in[1];
    const float* feat    = (const float*)d_in[4];
    const float* W       = (const float*)d_in[5];
    const float* attn_l  = (const float*)d_in[6];
    const float* attn_r  = (const float*)d_in[7];
    float* out = (float*)d_out;

    // ws: Wt 128KB | h_bf 25.6MB | arow 0.8MB | acol 0.8MB
    ushort* Wt   = (ushort*)d_ws;
    ushort* h_bf = Wt + 256 * 256;
    float*  arow = (float*)(h_bf + (size_t)N_NODES * HF);
    float*  acol = arow + (size_t)N_NODES * NH;

    const size_t need = (256 * 256 + (size_t)N_NODES * HF) * 2
                      + (size_t)N_NODES * NH * 4 * 2;
    if (ws_size < need) return;

    cast_wt_kernel<<<16, 256, 0, stream>>>(W, Wt);

    mfma_gemm_kernel<<<(N_NODES + 63) / 64, 256, 0, stream>>>(feat, Wt, attn_l, attn_r,
                                                              h_bf, arow, acol, N_NODES);

    agg_kernel<<<N_NODES / 8, 256, 0, stream>>>(col_ind, h_bf, arow, acol, out);
}